// Round 3
// baseline (279.322 us; speedup 1.0000x reference)
//
#include <hip/hip_runtime.h>

#define D 128
#define N_SRC 100000
#define N_DST 100000
#define N_EDGES 640000

#define SCAN_BLK 1024
#define N_SCAN_BLOCKS ((N_DST + SCAN_BLK - 1) / SCAN_BLK)   // 98

#define HIST_BLOCKS ((N_EDGES + 255) / 256)                 // 2500
#define CVT_BLOCKS  ((N_SRC * D / 8) / 256)                 // 6250 (exact)
#define PACKW_BLOCKS 128

typedef __attribute__((ext_vector_type(8))) short s8v;
typedef __attribute__((ext_vector_type(4))) float f32x4;

__device__ __forceinline__ unsigned short f2bf(float f) {
    unsigned int u = __float_as_uint(f);
    u += 0x7fffu + ((u >> 16) & 1u);   // round-to-nearest-even
    return (unsigned short)(u >> 16);
}

__device__ __forceinline__ unsigned int pk2(float a, float b) {
    return (unsigned int)f2bf(a) | ((unsigned int)f2bf(b) << 16);
}

// ---- prep: histogram + h_src->bf16 (into d_out rows [0,64) words) + pack W
__global__ __launch_bounds__(256) void prep(
    const int* __restrict__ dst_idx, int* __restrict__ counts,
    const float* __restrict__ h_src, unsigned int* __restrict__ A32,
    const float* __restrict__ W, unsigned short* __restrict__ Bp)
{
    const int blk = blockIdx.x;
    const int tid = threadIdx.x;
    if (blk < HIST_BLOCKS) {
        int e = blk * 256 + tid;
        if (e < N_EDGES) atomicAdd(&counts[dst_idx[e]], 1);
    } else if (blk < HIST_BLOCKS + CVT_BLOCKS) {
        // convert 8 f32 -> 8 bf16 per thread; dest = first 256 B of d_out row r
        int id = (blk - HIST_BLOCKS) * 256 + tid;      // [0, 1.6e6)
        size_t e = (size_t)id * 8;
        const float4* p = (const float4*)(h_src + e);
        float4 x = p[0], y = p[1];
        uint4 o;
        o.x = pk2(x.x, x.y); o.y = pk2(x.z, x.w);
        o.z = pk2(y.x, y.y); o.w = pk2(y.z, y.w);
        int r = id >> 4;            // 16 threads per 128-elem row
        int c = (id & 15) * 8;      // element offset within row
        *(uint4*)(A32 + (size_t)r * 128 + (c >> 1)) = o;
    } else {
        // pack W into MFMA B-fragment order (bf16)
        int id = (blk - HIST_BLOCKS - CVT_BLOCKS) * 256 + tid;
        if (id < 32768) {
            int j = id & 7;
            int l = (id >> 3) & 63;
            int t = (id >> 9) & 7;
            int s = id >> 12;
            int k = s * 32 + (l >> 4) * 8 + j;
            int n = t * 16 + (l & 15);
            Bp[id] = f2bf(W[k * D + n]);
        }
    }
}

// ---- CSR build ----------------------------------------------------------

__global__ __launch_bounds__(256) void scan_blocks(
    const int* __restrict__ counts, int* __restrict__ row_start,
    int* __restrict__ block_sums)
{
    __shared__ int sh[256];
    const int tid = threadIdx.x;
    const int base = blockIdx.x * SCAN_BLK + tid * 4;
    int v[4];
    int local = 0;
#pragma unroll
    for (int k = 0; k < 4; k++) {
        int idx = base + k;
        v[k] = (idx < N_DST) ? counts[idx] : 0;
        local += v[k];
    }
    sh[tid] = local;
    __syncthreads();
    for (int off = 1; off < 256; off <<= 1) {
        int t = (tid >= off) ? sh[tid - off] : 0;
        __syncthreads();
        sh[tid] += t;
        __syncthreads();
    }
    int run = (tid == 0) ? 0 : sh[tid - 1];
    if (tid == 255) block_sums[blockIdx.x] = sh[255];
#pragma unroll
    for (int k = 0; k < 4; k++) {
        int idx = base + k;
        if (idx < N_DST) row_start[idx] = run;
        run += v[k];
    }
}

__global__ __launch_bounds__(256) void add_offsets(
    int* __restrict__ row_start, const int* __restrict__ block_sums,
    int* __restrict__ cursor)
{
    __shared__ int sh[128];
    const int tid = threadIdx.x;
    if (tid < 128) sh[tid] = (tid < N_SCAN_BLOCKS) ? block_sums[tid] : 0;
    __syncthreads();
    for (int off = 1; off < 128; off <<= 1) {
        int t = (tid < 128 && tid >= off) ? sh[tid - off] : 0;
        __syncthreads();
        if (tid < 128) sh[tid] += t;
        __syncthreads();
    }
    int i = blockIdx.x * 256 + tid;
    if (i < N_DST) {
        int blk = i / SCAN_BLK;
        int off = (blk == 0) ? 0 : sh[blk - 1];
        int v = row_start[i] + off;
        row_start[i] = v;
        cursor[i] = v;
    }
    if (i == 0) row_start[N_DST] = N_EDGES;
}

__global__ __launch_bounds__(256) void scatter_perm(
    const int* __restrict__ src_idx, const int* __restrict__ dst_idx,
    int* __restrict__ cursor, int* __restrict__ edge_src)
{
    int e = blockIdx.x * 256 + threadIdx.x;
    if (e < N_EDGES) {
        int d = dst_idx[e];
        int pos = atomicAdd(&cursor[d], 1);
        edge_src[pos] = src_idx[e];
    }
}

// ---- Aggregation: FOUR destination rows per wave (one per 16-lane group).
// Each lane gathers 16 B (uint4) of a 256-B bf16 row: one VMEM instruction
// covers 4 edge-rows, 8-deep batching -> 32 row-loads in flight per wave.
__global__ __launch_bounds__(256) void aggregate(
    const unsigned short* __restrict__ hs16,   // d_out as u16: row r at r*256, elems [0,128)
    const int* __restrict__ row_start,
    const int* __restrict__ edge_src, unsigned int* __restrict__ A32)
{
    const int wave = threadIdx.x >> 6;
    const int grp = (threadIdx.x >> 4) & 3;
    const int gl = threadIdx.x & 15;
    const int row = blockIdx.x * 16 + wave * 4 + grp;
    const int start = row_start[row];
    const int deg = row_start[row + 1] - start;
    float acc[8] = {0.f, 0.f, 0.f, 0.f, 0.f, 0.f, 0.f, 0.f};
    for (int base = 0; base < deg; base += 8) {
        int j = base + (gl & 7);
        int myid = edge_src[start + min(j, deg - 1)];
#pragma unroll
        for (int t = 0; t < 8; t++) {
            int s = __shfl(myid, t, 16);   // broadcast within 16-lane group
            uint4 u = *(const uint4*)(hs16 + (size_t)s * 256 + gl * 8);
            float m = ((base + t) < deg) ? 1.f : 0.f;
            acc[0] = fmaf(__uint_as_float(u.x << 16), m, acc[0]);
            acc[1] = fmaf(__uint_as_float(u.x & 0xffff0000u), m, acc[1]);
            acc[2] = fmaf(__uint_as_float(u.y << 16), m, acc[2]);
            acc[3] = fmaf(__uint_as_float(u.y & 0xffff0000u), m, acc[3]);
            acc[4] = fmaf(__uint_as_float(u.z << 16), m, acc[4]);
            acc[5] = fmaf(__uint_as_float(u.z & 0xffff0000u), m, acc[5]);
            acc[6] = fmaf(__uint_as_float(u.w << 16), m, acc[6]);
            acc[7] = fmaf(__uint_as_float(u.w & 0xffff0000u), m, acc[7]);
        }
    }
    const float inv = 1.0f / fmaxf((float)deg, 1.0f);
    uint4 o;
    o.x = pk2(acc[0] * inv, acc[1] * inv);
    o.y = pk2(acc[2] * inv, acc[3] * inv);
    o.z = pk2(acc[4] * inv, acc[5] * inv);
    o.w = pk2(acc[6] * inv, acc[7] * inv);
    *(uint4*)(A32 + (size_t)row * 128 + 64 + gl * 4) = o;
}

// ---- Projection via MFMA 16x16x32 bf16 ----------------------------------
// Block = 64 rows x 128 cols; wave w = those 64 rows x cols [w*32, w*32+32).
// B fragments for the wave's two column tiles live in VGPRs, loaded ONCE
// (16 frags = 64 VGPR) -> W refetch drops from 400 MB to 100 MB. The 4
// waves read the same A rows -> 4x L1 reuse on h_dst. __syncthreads()
// between MFMA loop and epilogue: stores to out cols 64..127 alias the h_N
// halves other waves read.
__global__ __launch_bounds__(256, 3) void mfma_gemm(
    const float* __restrict__ h_dst,
    const unsigned short* __restrict__ A,   // d_out viewed as u16[N_DST][256]
    const unsigned short* __restrict__ Bp,  // packed W fragments (64 KB)
    const float* __restrict__ bias,
    float* __restrict__ out)
{
    const int wave = threadIdx.x >> 6;
    const int lane = threadIdx.x & 63;
    const int quad = lane >> 4;
    const int lr = lane & 15;
    const int row0 = blockIdx.x * 64;
    const int t0 = wave * 2;

    // B fragments, loaded once per wave.
    s8v Bf[8][2];
#pragma unroll
    for (int s = 0; s < 8; s++)
#pragma unroll
        for (int j = 0; j < 2; j++)
            Bf[s][j] = *(const s8v*)(Bp + ((size_t)(s * 8 + t0 + j) * 64 + lane) * 8);

    f32x4 acc[4][2];
#pragma unroll
    for (int rg = 0; rg < 4; rg++)
#pragma unroll
        for (int j = 0; j < 2; j++)
            acc[rg][j] = (f32x4){0.f, 0.f, 0.f, 0.f};

#pragma unroll
    for (int rg = 0; rg < 4; rg++) {
        int r = row0 + rg * 16 + lr;
        int rc = min(r, N_DST - 1);
        const float* p = h_dst + (size_t)rc * D + quad * 8;
        const unsigned short* q = A + (size_t)rc * 256 + 128 + quad * 8;

        float4 x[4], y[4];
        s8v an[4];
#pragma unroll
        for (int s = 0; s < 4; s++) {
            x[s] = *(const float4*)(p + s * 32);
            y[s] = *(const float4*)(p + s * 32 + 4);
            an[s] = *(const s8v*)(q + s * 32);
        }
#pragma unroll
        for (int s = 0; s < 8; s++) {
            s8v a0;
            if (s < 4) {
                unsigned short au[8];
                au[0] = f2bf(x[s].x); au[1] = f2bf(x[s].y);
                au[2] = f2bf(x[s].z); au[3] = f2bf(x[s].w);
                au[4] = f2bf(y[s].x); au[5] = f2bf(y[s].y);
                au[6] = f2bf(y[s].z); au[7] = f2bf(y[s].w);
                a0 = *(s8v*)au;
            } else {
                a0 = an[s - 4];
            }
            acc[rg][0] = __builtin_amdgcn_mfma_f32_16x16x32_bf16(a0, Bf[s][0], acc[rg][0], 0, 0, 0);
            acc[rg][1] = __builtin_amdgcn_mfma_f32_16x16x32_bf16(a0, Bf[s][1], acc[rg][1], 0, 0, 0);
        }
    }

    // All h_N reads (q loads) are consumed above; barrier before any wave
    // overwrites this block's rows with f32 output.
    __syncthreads();

    float bv0 = bias[t0 * 16 + lr];
    float bv1 = bias[(t0 + 1) * 16 + lr];
#pragma unroll
    for (int rg = 0; rg < 4; rg++) {
#pragma unroll
        for (int r = 0; r < 4; r++) {
            int row = row0 + rg * 16 + quad * 4 + r;
            if (row < N_DST) {
                out[(size_t)row * D + t0 * 16 + lr] = acc[rg][0][r] + bv0;
                out[(size_t)row * D + (t0 + 1) * 16 + lr] = acc[rg][1][r] + bv1;
            }
        }
    }
}

extern "C" void kernel_launch(void* const* d_in, const int* in_sizes, int n_in,
                              void* d_out, int out_size, void* d_ws, size_t ws_size,
                              hipStream_t stream) {
    const float* h_src  = (const float*)d_in[0];
    const float* h_dst  = (const float*)d_in[1];
    const int* src_idx  = (const int*)d_in[2];
    const int* dst_idx  = (const int*)d_in[3];
    const float* W      = (const float*)d_in[4];
    const float* b      = (const float*)d_in[5];
    float* out = (float*)d_out;

    // Workspace: Bp first (16B-aligned), then CSR int arrays (~3.9 MB total)
    unsigned short* Bp = (unsigned short*)d_ws;         // 32768 u16 = 64 KB
    int* ws_i          = (int*)((char*)d_ws + 65536);
    int* row_start     = ws_i;                          // N_DST+1
    int* cursor        = row_start + (N_DST + 1);       // N_DST
    int* counts        = cursor + N_DST;                // N_DST
    int* block_sums    = counts + N_DST;                // N_SCAN_BLOCKS
    int* edge_src      = block_sums + N_SCAN_BLOCKS;    // N_EDGES

    hipMemsetAsync(counts, 0, (size_t)N_DST * sizeof(int), stream);

    // hist + h_src->bf16 (into d_out first halves) + pack_W, one launch
    prep<<<HIST_BLOCKS + CVT_BLOCKS + PACKW_BLOCKS, 256, 0, stream>>>(
        dst_idx, counts, h_src, (unsigned int*)d_out, W, Bp);

    scan_blocks<<<N_SCAN_BLOCKS, 256, 0, stream>>>(counts, row_start, block_sums);
    add_offsets<<<(N_DST + 255) / 256, 256, 0, stream>>>(row_start, block_sums, cursor);
    scatter_perm<<<(N_EDGES + 255) / 256, 256, 0, stream>>>(src_idx, dst_idx, cursor, edge_src);

    aggregate<<<N_DST / 16, 256, 0, stream>>>(
        (const unsigned short*)d_out, row_start, edge_src, (unsigned int*)d_out);

    int gemm_blocks = (N_DST + 63) / 64;   // 1563 blocks of 4 waves
    mfma_gemm<<<gemm_blocks, 256, 0, stream>>>(
        h_dst, (const unsigned short*)d_out, Bp, b, out);
}

// Round 4
// 264.403 us; speedup vs baseline: 1.0564x; 1.0564x over previous
//
#include <hip/hip_runtime.h>

#define D 128
#define N_SRC 100000
#define N_DST 100000
#define N_EDGES 640000

#define SCAN_BLK 1024
#define N_SCAN_BLOCKS ((N_DST + SCAN_BLK - 1) / SCAN_BLK)   // 98

#define HIST_BLOCKS ((N_EDGES + 255) / 256)                 // 2500
#define CVT_BLOCKS  ((N_SRC * D / 8) / 256)                 // 6250 (exact)
#define PACKW_BLOCKS 128

typedef __attribute__((ext_vector_type(8))) short s8v;
typedef __attribute__((ext_vector_type(4))) float f32x4;

__device__ __forceinline__ unsigned short f2bf(float f) {
    unsigned int u = __float_as_uint(f);
    u += 0x7fffu + ((u >> 16) & 1u);   // round-to-nearest-even
    return (unsigned short)(u >> 16);
}

__device__ __forceinline__ unsigned int pk2(float a, float b) {
    return (unsigned int)f2bf(a) | ((unsigned int)f2bf(b) << 16);
}

// ---- prep: histogram + h_src->bf16 (into d_out rows [0,64) words) + pack W
__global__ __launch_bounds__(256) void prep(
    const int* __restrict__ dst_idx, int* __restrict__ counts,
    const float* __restrict__ h_src, unsigned int* __restrict__ A32,
    const float* __restrict__ W, unsigned short* __restrict__ Bp)
{
    const int blk = blockIdx.x;
    const int tid = threadIdx.x;
    if (blk < HIST_BLOCKS) {
        int e = blk * 256 + tid;
        if (e < N_EDGES) atomicAdd(&counts[dst_idx[e]], 1);
    } else if (blk < HIST_BLOCKS + CVT_BLOCKS) {
        // convert 8 f32 -> 8 bf16 per thread; dest = first 256 B of d_out row r
        int id = (blk - HIST_BLOCKS) * 256 + tid;      // [0, 1.6e6)
        size_t e = (size_t)id * 8;
        const float4* p = (const float4*)(h_src + e);
        float4 x = p[0], y = p[1];
        uint4 o;
        o.x = pk2(x.x, x.y); o.y = pk2(x.z, x.w);
        o.z = pk2(y.x, y.y); o.w = pk2(y.z, y.w);
        int r = id >> 4;            // 16 threads per 128-elem row
        int c = (id & 15) * 8;      // element offset within row
        *(uint4*)(A32 + (size_t)r * 128 + (c >> 1)) = o;
    } else {
        // pack W into MFMA B-fragment order (bf16)
        int id = (blk - HIST_BLOCKS - CVT_BLOCKS) * 256 + tid;
        if (id < 32768) {
            int j = id & 7;
            int l = (id >> 3) & 63;
            int t = (id >> 9) & 7;
            int s = id >> 12;
            int k = s * 32 + (l >> 4) * 8 + j;
            int n = t * 16 + (l & 15);
            Bp[id] = f2bf(W[k * D + n]);
        }
    }
}

// ---- CSR build ----------------------------------------------------------

__global__ __launch_bounds__(256) void scan_blocks(
    const int* __restrict__ counts, int* __restrict__ row_start,
    int* __restrict__ block_sums)
{
    __shared__ int sh[256];
    const int tid = threadIdx.x;
    const int base = blockIdx.x * SCAN_BLK + tid * 4;
    int v[4];
    int local = 0;
#pragma unroll
    for (int k = 0; k < 4; k++) {
        int idx = base + k;
        v[k] = (idx < N_DST) ? counts[idx] : 0;
        local += v[k];
    }
    sh[tid] = local;
    __syncthreads();
    for (int off = 1; off < 256; off <<= 1) {
        int t = (tid >= off) ? sh[tid - off] : 0;
        __syncthreads();
        sh[tid] += t;
        __syncthreads();
    }
    int run = (tid == 0) ? 0 : sh[tid - 1];
    if (tid == 255) block_sums[blockIdx.x] = sh[255];
#pragma unroll
    for (int k = 0; k < 4; k++) {
        int idx = base + k;
        if (idx < N_DST) row_start[idx] = run;
        run += v[k];
    }
}

__global__ __launch_bounds__(256) void add_offsets(
    int* __restrict__ row_start, const int* __restrict__ block_sums,
    int* __restrict__ cursor)
{
    __shared__ int sh[128];
    const int tid = threadIdx.x;
    if (tid < 128) sh[tid] = (tid < N_SCAN_BLOCKS) ? block_sums[tid] : 0;
    __syncthreads();
    for (int off = 1; off < 128; off <<= 1) {
        int t = (tid < 128 && tid >= off) ? sh[tid - off] : 0;
        __syncthreads();
        if (tid < 128) sh[tid] += t;
        __syncthreads();
    }
    int i = blockIdx.x * 256 + tid;
    if (i < N_DST) {
        int blk = i / SCAN_BLK;
        int off = (blk == 0) ? 0 : sh[blk - 1];
        int v = row_start[i] + off;
        row_start[i] = v;
        cursor[i] = v;
    }
    if (i == 0) row_start[N_DST] = N_EDGES;
}

__global__ __launch_bounds__(256) void scatter_perm(
    const int* __restrict__ src_idx, const int* __restrict__ dst_idx,
    int* __restrict__ cursor, int* __restrict__ edge_src)
{
    int e = blockIdx.x * 256 + threadIdx.x;
    if (e < N_EDGES) {
        int d = dst_idx[e];
        int pos = atomicAdd(&cursor[d], 1);
        edge_src[pos] = src_idx[e];
    }
}

// ---- Aggregation: FOUR destination rows per wave (one per 16-lane group).
__global__ __launch_bounds__(256) void aggregate(
    const unsigned short* __restrict__ hs16,   // d_out as u16: row r at r*256, elems [0,128)
    const int* __restrict__ row_start,
    const int* __restrict__ edge_src, unsigned int* __restrict__ A32)
{
    const int wave = threadIdx.x >> 6;
    const int grp = (threadIdx.x >> 4) & 3;
    const int gl = threadIdx.x & 15;
    const int row = blockIdx.x * 16 + wave * 4 + grp;
    const int start = row_start[row];
    const int deg = row_start[row + 1] - start;
    float acc[8] = {0.f, 0.f, 0.f, 0.f, 0.f, 0.f, 0.f, 0.f};
    for (int base = 0; base < deg; base += 8) {
        int j = base + (gl & 7);
        int myid = edge_src[start + min(j, deg - 1)];
#pragma unroll
        for (int t = 0; t < 8; t++) {
            int s = __shfl(myid, t, 16);   // broadcast within 16-lane group
            uint4 u = *(const uint4*)(hs16 + (size_t)s * 256 + gl * 8);
            float m = ((base + t) < deg) ? 1.f : 0.f;
            acc[0] = fmaf(__uint_as_float(u.x << 16), m, acc[0]);
            acc[1] = fmaf(__uint_as_float(u.x & 0xffff0000u), m, acc[1]);
            acc[2] = fmaf(__uint_as_float(u.y << 16), m, acc[2]);
            acc[3] = fmaf(__uint_as_float(u.y & 0xffff0000u), m, acc[3]);
            acc[4] = fmaf(__uint_as_float(u.z << 16), m, acc[4]);
            acc[5] = fmaf(__uint_as_float(u.z & 0xffff0000u), m, acc[5]);
            acc[6] = fmaf(__uint_as_float(u.w << 16), m, acc[6]);
            acc[7] = fmaf(__uint_as_float(u.w & 0xffff0000u), m, acc[7]);
        }
    }
    const float inv = 1.0f / fmaxf((float)deg, 1.0f);
    uint4 o;
    o.x = pk2(acc[0] * inv, acc[1] * inv);
    o.y = pk2(acc[2] * inv, acc[3] * inv);
    o.z = pk2(acc[4] * inv, acc[5] * inv);
    o.w = pk2(acc[6] * inv, acc[7] * inv);
    *(uint4*)(A32 + (size_t)row * 128 + 64 + gl * 4) = o;
}

// ---- Projection via MFMA 16x16x32 bf16, B staged in LDS -----------------
// Block = 4 waves x 32 rows = 128 rows; each wave covers all 128 cols.
// W fragments come from LDS (ds_read_b128, can't be sunk to global by the
// allocator, ~10x lower latency than L2). K-split: stage s=0..3 half
// (32 KB) -> compute -> restage s=4..7 half -> compute. Each wave reads
// h_N only from its OWN 32 rows, so stores need no extra barrier.
__global__ __launch_bounds__(256, 2) void mfma_gemm(
    const float* __restrict__ h_dst,
    const unsigned short* __restrict__ A,   // d_out viewed as u16[N_DST][256]
    const unsigned short* __restrict__ Bp,  // packed W fragments (64 KB)
    const float* __restrict__ bias,
    float* __restrict__ out)
{
    __shared__ uint4 Bs4[2048];             // 32 KB: one K-half of packed W
    unsigned short* Bs = (unsigned short*)Bs4;
    const int tid = threadIdx.x;
    const int wave = tid >> 6;
    const int lane = tid & 63;
    const int quad = lane >> 4;
    const int lr = lane & 15;
    const int row0 = blockIdx.x * 128 + wave * 32;

    const int r0 = min(row0 + lr, N_DST - 1);
    const int r1 = min(row0 + 16 + lr, N_DST - 1);

    // ---- stage K-half 0 (frags s=0..3)
    {
        const uint4* src = (const uint4*)Bp;
#pragma unroll
        for (int i = 0; i < 8; i++)
            Bs4[tid + i * 256] = src[tid + i * 256];
    }

    // ---- issue A loads (h_dst f32) and h_N loads; convert h_dst to frags
    const float* p0 = h_dst + (size_t)r0 * D + quad * 8;
    const float* p1 = h_dst + (size_t)r1 * D + quad * 8;
    const unsigned short* q0 = A + (size_t)r0 * 256 + 128 + quad * 8;
    const unsigned short* q1 = A + (size_t)r1 * 256 + 128 + quad * 8;

    float4 x0[4], y0[4], x1[4], y1[4];
    s8v an0[4], an1[4];
#pragma unroll
    for (int s = 0; s < 4; s++) {
        x0[s] = *(const float4*)(p0 + s * 32);
        y0[s] = *(const float4*)(p0 + s * 32 + 4);
        x1[s] = *(const float4*)(p1 + s * 32);
        y1[s] = *(const float4*)(p1 + s * 32 + 4);
        an0[s] = *(const s8v*)(q0 + s * 32);
        an1[s] = *(const s8v*)(q1 + s * 32);
    }
    s8v af0[4], af1[4];
#pragma unroll
    for (int s = 0; s < 4; s++) {
        unsigned short u0[8], u1[8];
        u0[0]=f2bf(x0[s].x); u0[1]=f2bf(x0[s].y); u0[2]=f2bf(x0[s].z); u0[3]=f2bf(x0[s].w);
        u0[4]=f2bf(y0[s].x); u0[5]=f2bf(y0[s].y); u0[6]=f2bf(y0[s].z); u0[7]=f2bf(y0[s].w);
        u1[0]=f2bf(x1[s].x); u1[1]=f2bf(x1[s].y); u1[2]=f2bf(x1[s].z); u1[3]=f2bf(x1[s].w);
        u1[4]=f2bf(y1[s].x); u1[5]=f2bf(y1[s].y); u1[6]=f2bf(y1[s].z); u1[7]=f2bf(y1[s].w);
        af0[s] = *(s8v*)u0;
        af1[s] = *(s8v*)u1;
    }

    f32x4 acc0[8], acc1[8];
#pragma unroll
    for (int t = 0; t < 8; t++) {
        acc0[t] = (f32x4){0.f, 0.f, 0.f, 0.f};
        acc1[t] = (f32x4){0.f, 0.f, 0.f, 0.f};
    }

    __syncthreads();   // Bs half 0 ready (also drains A loads)

    // ---- phase 0: K = 0..127 (h_dst)
#pragma unroll
    for (int s = 0; s < 4; s++) {
#pragma unroll
        for (int t = 0; t < 8; t++) {
            s8v bf = *(const s8v*)(Bs + ((s * 8 + t) * 64 + lane) * 8);
            acc0[t] = __builtin_amdgcn_mfma_f32_16x16x32_bf16(af0[s], bf, acc0[t], 0, 0, 0);
            acc1[t] = __builtin_amdgcn_mfma_f32_16x16x32_bf16(af1[s], bf, acc1[t], 0, 0, 0);
        }
    }

    __syncthreads();   // all waves done reading half 0

    // ---- stage K-half 1 (frags s=4..7)
    {
        const uint4* src = (const uint4*)(Bp + 16384);
#pragma unroll
        for (int i = 0; i < 8; i++)
            Bs4[tid + i * 256] = src[tid + i * 256];
    }
    __syncthreads();   // Bs half 1 ready

    // ---- phase 1: K = 128..255 (h_N, already bf16)
#pragma unroll
    for (int s = 0; s < 4; s++) {
#pragma unroll
        for (int t = 0; t < 8; t++) {
            s8v bf = *(const s8v*)(Bs + ((s * 8 + t) * 64 + lane) * 8);
            acc0[t] = __builtin_amdgcn_mfma_f32_16x16x32_bf16(an0[s], bf, acc0[t], 0, 0, 0);
            acc1[t] = __builtin_amdgcn_mfma_f32_16x16x32_bf16(an1[s], bf, acc1[t], 0, 0, 0);
        }
    }

    // ---- epilogue: bias + f32 stores (own rows only)
#pragma unroll
    for (int t = 0; t < 8; t++) {
        float bv = bias[t * 16 + lr];
#pragma unroll
        for (int r = 0; r < 4; r++) {
            int rowa = row0 + quad * 4 + r;
            int rowb = row0 + 16 + quad * 4 + r;
            if (rowa < N_DST) out[(size_t)rowa * D + t * 16 + lr] = acc0[t][r] + bv;
            if (rowb < N_DST) out[(size_t)rowb * D + t * 16 + lr] = acc1[t][r] + bv;
        }
    }
}

extern "C" void kernel_launch(void* const* d_in, const int* in_sizes, int n_in,
                              void* d_out, int out_size, void* d_ws, size_t ws_size,
                              hipStream_t stream) {
    const float* h_src  = (const float*)d_in[0];
    const float* h_dst  = (const float*)d_in[1];
    const int* src_idx  = (const int*)d_in[2];
    const int* dst_idx  = (const int*)d_in[3];
    const float* W      = (const float*)d_in[4];
    const float* b      = (const float*)d_in[5];
    float* out = (float*)d_out;

    // Workspace: Bp first (16B-aligned), then CSR int arrays (~3.9 MB total)
    unsigned short* Bp = (unsigned short*)d_ws;         // 32768 u16 = 64 KB
    int* ws_i          = (int*)((char*)d_ws + 65536);
    int* row_start     = ws_i;                          // N_DST+1
    int* cursor        = row_start + (N_DST + 1);       // N_DST
    int* counts        = cursor + N_DST;                // N_DST
    int* block_sums    = counts + N_DST;                // N_SCAN_BLOCKS
    int* edge_src      = block_sums + N_SCAN_BLOCKS;    // N_EDGES

    hipMemsetAsync(counts, 0, (size_t)N_DST * sizeof(int), stream);

    // hist + h_src->bf16 (into d_out first halves) + pack_W, one launch
    prep<<<HIST_BLOCKS + CVT_BLOCKS + PACKW_BLOCKS, 256, 0, stream>>>(
        dst_idx, counts, h_src, (unsigned int*)d_out, W, Bp);

    scan_blocks<<<N_SCAN_BLOCKS, 256, 0, stream>>>(counts, row_start, block_sums);
    add_offsets<<<(N_DST + 255) / 256, 256, 0, stream>>>(row_start, block_sums, cursor);
    scatter_perm<<<(N_EDGES + 255) / 256, 256, 0, stream>>>(src_idx, dst_idx, cursor, edge_src);

    aggregate<<<N_DST / 16, 256, 0, stream>>>(
        (const unsigned short*)d_out, row_start, edge_src, (unsigned int*)d_out);

    int gemm_blocks = (N_DST + 127) / 128;   // 782 blocks of 4 waves (128 rows)
    mfma_gemm<<<gemm_blocks, 256, 0, stream>>>(
        h_dst, (const unsigned short*)d_out, Bp, b, out);
}

// Round 5
// 260.727 us; speedup vs baseline: 1.0713x; 1.0141x over previous
//
#include <hip/hip_runtime.h>

#define D 128
#define N_SRC 100000
#define N_DST 100000
#define N_EDGES 640000

#define SCAN_BLK 1024
#define N_SCAN_BLOCKS ((N_DST + SCAN_BLK - 1) / SCAN_BLK)   // 98

#define HIST_BLOCKS ((N_EDGES + 255) / 256)                 // 2500
#define CVT_BLOCKS  ((N_SRC * D / 8) / 256)                 // 6250 (exact)
#define PACKW_BLOCKS 128

typedef __attribute__((ext_vector_type(8))) short s8v;
typedef __attribute__((ext_vector_type(4))) float f32x4;

__device__ __forceinline__ unsigned short f2bf(float f) {
    unsigned int u = __float_as_uint(f);
    u += 0x7fffu + ((u >> 16) & 1u);   // round-to-nearest-even
    return (unsigned short)(u >> 16);
}

__device__ __forceinline__ unsigned int pk2(float a, float b) {
    return (unsigned int)f2bf(a) | ((unsigned int)f2bf(b) << 16);
}

// ---- prep: histogram + h_src->bf16 mirror + pack W ----------------------
// mir32/mir_stride32 parameterize the mirror destination:
//   fused path:    dense ws mirror, stride 64 u32 (256 B rows)
//   fallback path: d_out first halves, stride 128 u32 (512 B rows)
__global__ __launch_bounds__(256) void prep(
    const int* __restrict__ dst_idx, int* __restrict__ counts,
    const float* __restrict__ h_src, unsigned int* __restrict__ mir32,
    int mir_stride32,
    const float* __restrict__ W, unsigned short* __restrict__ Bp)
{
    const int blk = blockIdx.x;
    const int tid = threadIdx.x;
    if (blk < HIST_BLOCKS) {
        int e = blk * 256 + tid;
        if (e < N_EDGES) atomicAdd(&counts[dst_idx[e]], 1);
    } else if (blk < HIST_BLOCKS + CVT_BLOCKS) {
        int id = (blk - HIST_BLOCKS) * 256 + tid;      // [0, 1.6e6)
        size_t e = (size_t)id * 8;
        const float4* p = (const float4*)(h_src + e);
        float4 x = p[0], y = p[1];
        uint4 o;
        o.x = pk2(x.x, x.y); o.y = pk2(x.z, x.w);
        o.z = pk2(y.x, y.y); o.w = pk2(y.z, y.w);
        int r = id >> 4;            // 16 threads per 128-elem row
        int c = (id & 15) * 8;      // element offset within row
        *(uint4*)(mir32 + (size_t)r * mir_stride32 + (c >> 1)) = o;
    } else {
        // pack W into MFMA B-fragment order (bf16)
        int id = (blk - HIST_BLOCKS - CVT_BLOCKS) * 256 + tid;
        if (id < 32768) {
            int j = id & 7;
            int l = (id >> 3) & 63;
            int t = (id >> 9) & 7;
            int s = id >> 12;
            int k = s * 32 + (l >> 4) * 8 + j;
            int n = t * 16 + (l & 15);
            Bp[id] = f2bf(W[k * D + n]);
        }
    }
}

// ---- CSR build ----------------------------------------------------------

__global__ __launch_bounds__(256) void scan_blocks(
    const int* __restrict__ counts, int* __restrict__ row_start,
    int* __restrict__ block_sums)
{
    __shared__ int sh[256];
    const int tid = threadIdx.x;
    const int base = blockIdx.x * SCAN_BLK + tid * 4;
    int v[4];
    int local = 0;
#pragma unroll
    for (int k = 0; k < 4; k++) {
        int idx = base + k;
        v[k] = (idx < N_DST) ? counts[idx] : 0;
        local += v[k];
    }
    sh[tid] = local;
    __syncthreads();
    for (int off = 1; off < 256; off <<= 1) {
        int t = (tid >= off) ? sh[tid - off] : 0;
        __syncthreads();
        sh[tid] += t;
        __syncthreads();
    }
    int run = (tid == 0) ? 0 : sh[tid - 1];
    if (tid == 255) block_sums[blockIdx.x] = sh[255];
#pragma unroll
    for (int k = 0; k < 4; k++) {
        int idx = base + k;
        if (idx < N_DST) row_start[idx] = run;
        run += v[k];
    }
}

__global__ __launch_bounds__(256) void add_offsets(
    int* __restrict__ row_start, const int* __restrict__ block_sums,
    int* __restrict__ cursor)
{
    __shared__ int sh[128];
    const int tid = threadIdx.x;
    if (tid < 128) sh[tid] = (tid < N_SCAN_BLOCKS) ? block_sums[tid] : 0;
    __syncthreads();
    for (int off = 1; off < 128; off <<= 1) {
        int t = (tid < 128 && tid >= off) ? sh[tid - off] : 0;
        __syncthreads();
        if (tid < 128) sh[tid] += t;
        __syncthreads();
    }
    int i = blockIdx.x * 256 + tid;
    if (i < N_DST) {
        int blk = i / SCAN_BLK;
        int off = (blk == 0) ? 0 : sh[blk - 1];
        int v = row_start[i] + off;
        row_start[i] = v;
        cursor[i] = v;
    }
    if (i == 0) row_start[N_DST] = N_EDGES;
}

__global__ __launch_bounds__(256) void scatter_perm(
    const int* __restrict__ src_idx, const int* __restrict__ dst_idx,
    int* __restrict__ cursor, int* __restrict__ edge_src)
{
    int e = blockIdx.x * 256 + threadIdx.x;
    if (e < N_EDGES) {
        int d = dst_idx[e];
        int pos = atomicAdd(&cursor[d], 1);
        edge_src[pos] = src_idx[e];
    }
}

// ======================== FUSED PATH (ws mirror) =========================
// Block = 4 waves x 16 rows = 64 rows. Per block:
//   gather h_N for own rows from dense bf16 mirror -> LDS (16 KB, swizzled)
//   MFMA projection: K=0..127 from h_dst (global f32 -> cvt), K=128..255
//   from LDS h_N; B staged in LDS in two 32-KB K-halves.
// h_N never touches HBM. No cross-block hazards: mirror is immutable,
// each wave reads only its own rows' h_N (which it wrote itself).
__global__ __launch_bounds__(256, 3) void fused_ag(
    const float* __restrict__ h_dst,
    const unsigned short* __restrict__ mir,   // dense [N_SRC][128] bf16
    const int* __restrict__ row_start,
    const int* __restrict__ edge_src,
    const unsigned short* __restrict__ Bp,
    const float* __restrict__ bias,
    float* __restrict__ out)
{
    __shared__ uint4 Bs4[2048];              // 32 KB: one K-half of packed W
    __shared__ uint4 hN4[1024];              // 16 KB: h_N[64 rows][256 B]
    unsigned short* Bs = (unsigned short*)Bs4;
    char* hN = (char*)hN4;

    const int tid = threadIdx.x;
    const int wave = tid >> 6;
    const int lane = tid & 63;
    const int quad = lane >> 4;
    const int lr = lane & 15;
    const int rw0 = blockIdx.x * 64 + wave * 16;   // wave's first row

    // ---- stage B half 0 (frags s=0..3)
    {
        const uint4* src = (const uint4*)Bp;
#pragma unroll
        for (int i = 0; i < 8; i++)
            Bs4[tid + i * 256] = src[tid + i * 256];
    }

    // ---- issue h_dst loads for the wave's 16 rows (land during gather)
    const int r0 = min(rw0 + lr, N_DST - 1);
    const float* p0 = h_dst + (size_t)r0 * D + quad * 8;
    float4 x0[4], y0[4];
#pragma unroll
    for (int s = 0; s < 4; s++) {
        x0[s] = *(const float4*)(p0 + s * 32);
        y0[s] = *(const float4*)(p0 + s * 32 + 4);
    }

    // ---- gather phase: 4 iterations x 4 rows (one row per 16-lane quad)
#pragma unroll
    for (int i = 0; i < 4; i++) {
        int rl = wave * 16 + i * 4 + quad;          // local row 0..63
        int row = min(blockIdx.x * 64 + rl, N_DST - 1);
        int start = row_start[row];
        int deg = row_start[row + 1] - start;
        float a[8] = {0.f, 0.f, 0.f, 0.f, 0.f, 0.f, 0.f, 0.f};
        for (int base = 0; base < deg; base += 8) {
            int j = base + (lr & 7);
            int myid = edge_src[start + min(j, deg - 1)];
#pragma unroll
            for (int t = 0; t < 8; t++) {
                int s = __shfl(myid, t, 16);
                uint4 u = *(const uint4*)(mir + (size_t)s * 128 + lr * 8);
                float m = ((base + t) < deg) ? 1.f : 0.f;
                a[0] = fmaf(__uint_as_float(u.x << 16), m, a[0]);
                a[1] = fmaf(__uint_as_float(u.x & 0xffff0000u), m, a[1]);
                a[2] = fmaf(__uint_as_float(u.y << 16), m, a[2]);
                a[3] = fmaf(__uint_as_float(u.y & 0xffff0000u), m, a[3]);
                a[4] = fmaf(__uint_as_float(u.z << 16), m, a[4]);
                a[5] = fmaf(__uint_as_float(u.z & 0xffff0000u), m, a[5]);
                a[6] = fmaf(__uint_as_float(u.w << 16), m, a[6]);
                a[7] = fmaf(__uint_as_float(u.w & 0xffff0000u), m, a[7]);
            }
        }
        float inv = 1.0f / fmaxf((float)deg, 1.0f);
        uint4 o;
        o.x = pk2(a[0] * inv, a[1] * inv);
        o.y = pk2(a[2] * inv, a[3] * inv);
        o.z = pk2(a[4] * inv, a[5] * inv);
        o.w = pk2(a[6] * inv, a[7] * inv);
        // XOR-swizzled LDS write (bits 4-6) -> conflict-free frag reads later
        int ba = (rl * 256 + lr * 16) ^ ((rl & 7) << 4);
        *(uint4*)(hN + ba) = o;
    }

    // ---- convert h_dst to A fragments (half 0)
    s8v af0[4];
#pragma unroll
    for (int s = 0; s < 4; s++) {
        unsigned short u0[8];
        u0[0]=f2bf(x0[s].x); u0[1]=f2bf(x0[s].y); u0[2]=f2bf(x0[s].z); u0[3]=f2bf(x0[s].w);
        u0[4]=f2bf(y0[s].x); u0[5]=f2bf(y0[s].y); u0[6]=f2bf(y0[s].z); u0[7]=f2bf(y0[s].w);
        af0[s] = *(s8v*)u0;
    }

    f32x4 acc[8];
#pragma unroll
    for (int t = 0; t < 8; t++) acc[t] = (f32x4){0.f, 0.f, 0.f, 0.f};

    __syncthreads();   // B half 0 + all hN writes visible

    // ---- phase 0: K = 0..127 (h_dst)
#pragma unroll
    for (int s = 0; s < 4; s++) {
#pragma unroll
        for (int t = 0; t < 8; t++) {
            s8v bf = *(const s8v*)(Bs + ((s * 8 + t) * 64 + lane) * 8);
            acc[t] = __builtin_amdgcn_mfma_f32_16x16x32_bf16(af0[s], bf, acc[t], 0, 0, 0);
        }
    }

    __syncthreads();   // all waves done reading B half 0

    // ---- stage B half 1 (frags s=4..7)
    {
        const uint4* src = (const uint4*)(Bp + 16384);
#pragma unroll
        for (int i = 0; i < 8; i++)
            Bs4[tid + i * 256] = src[tid + i * 256];
    }

    // ---- read own h_N fragments (separate LDS region, no alias with Bs)
    s8v an[4];
#pragma unroll
    for (int s = 0; s < 4; s++) {
        int rl = wave * 16 + lr;
        int ba = (rl * 256 + s * 64 + quad * 16) ^ ((rl & 7) << 4);
        an[s] = *(const s8v*)(hN + ba);
    }
    __syncthreads();   // B half 1 ready

    // ---- phase 1: K = 128..255 (h_N)
#pragma unroll
    for (int s = 0; s < 4; s++) {
#pragma unroll
        for (int t = 0; t < 8; t++) {
            s8v bf = *(const s8v*)(Bs + ((s * 8 + t) * 64 + lane) * 8);
            acc[t] = __builtin_amdgcn_mfma_f32_16x16x32_bf16(an[s], bf, acc[t], 0, 0, 0);
        }
    }

    // ---- epilogue
#pragma unroll
    for (int t = 0; t < 8; t++) {
        float bv = bias[t * 16 + lr];
#pragma unroll
        for (int r = 0; r < 4; r++) {
            int row = rw0 + quad * 4 + r;
            if (row < N_DST) out[(size_t)row * D + t * 16 + lr] = acc[t][r] + bv;
        }
    }
}

// ======================= FALLBACK PATH (d_out mirror) ====================
// Identical to the round-4 kernels (mirror in d_out first halves, h_N via
// HBM round-trip). Used only when ws_size can't hold the dense mirror.

__global__ __launch_bounds__(256) void aggregate(
    const unsigned short* __restrict__ hs16,   // d_out as u16: row r at r*256
    const int* __restrict__ row_start,
    const int* __restrict__ edge_src, unsigned int* __restrict__ A32)
{
    const int wave = threadIdx.x >> 6;
    const int grp = (threadIdx.x >> 4) & 3;
    const int gl = threadIdx.x & 15;
    const int row = blockIdx.x * 16 + wave * 4 + grp;
    const int start = row_start[row];
    const int deg = row_start[row + 1] - start;
    float acc[8] = {0.f, 0.f, 0.f, 0.f, 0.f, 0.f, 0.f, 0.f};
    for (int base = 0; base < deg; base += 8) {
        int j = base + (gl & 7);
        int myid = edge_src[start + min(j, deg - 1)];
#pragma unroll
        for (int t = 0; t < 8; t++) {
            int s = __shfl(myid, t, 16);
            uint4 u = *(const uint4*)(hs16 + (size_t)s * 256 + gl * 8);
            float m = ((base + t) < deg) ? 1.f : 0.f;
            acc[0] = fmaf(__uint_as_float(u.x << 16), m, acc[0]);
            acc[1] = fmaf(__uint_as_float(u.x & 0xffff0000u), m, acc[1]);
            acc[2] = fmaf(__uint_as_float(u.y << 16), m, acc[2]);
            acc[3] = fmaf(__uint_as_float(u.y & 0xffff0000u), m, acc[3]);
            acc[4] = fmaf(__uint_as_float(u.z << 16), m, acc[4]);
            acc[5] = fmaf(__uint_as_float(u.z & 0xffff0000u), m, acc[5]);
            acc[6] = fmaf(__uint_as_float(u.w << 16), m, acc[6]);
            acc[7] = fmaf(__uint_as_float(u.w & 0xffff0000u), m, acc[7]);
        }
    }
    const float inv = 1.0f / fmaxf((float)deg, 1.0f);
    uint4 o;
    o.x = pk2(acc[0] * inv, acc[1] * inv);
    o.y = pk2(acc[2] * inv, acc[3] * inv);
    o.z = pk2(acc[4] * inv, acc[5] * inv);
    o.w = pk2(acc[6] * inv, acc[7] * inv);
    *(uint4*)(A32 + (size_t)row * 128 + 64 + gl * 4) = o;
}

__global__ __launch_bounds__(256, 2) void mfma_gemm(
    const float* __restrict__ h_dst,
    const unsigned short* __restrict__ A,   // d_out viewed as u16[N_DST][256]
    const unsigned short* __restrict__ Bp,
    const float* __restrict__ bias,
    float* __restrict__ out)
{
    __shared__ uint4 Bs4[2048];
    unsigned short* Bs = (unsigned short*)Bs4;
    const int tid = threadIdx.x;
    const int wave = tid >> 6;
    const int lane = tid & 63;
    const int quad = lane >> 4;
    const int lr = lane & 15;
    const int row0 = blockIdx.x * 128 + wave * 32;

    const int r0 = min(row0 + lr, N_DST - 1);
    const int r1 = min(row0 + 16 + lr, N_DST - 1);

    {
        const uint4* src = (const uint4*)Bp;
#pragma unroll
        for (int i = 0; i < 8; i++)
            Bs4[tid + i * 256] = src[tid + i * 256];
    }

    const float* p0 = h_dst + (size_t)r0 * D + quad * 8;
    const float* p1 = h_dst + (size_t)r1 * D + quad * 8;
    const unsigned short* q0 = A + (size_t)r0 * 256 + 128 + quad * 8;
    const unsigned short* q1 = A + (size_t)r1 * 256 + 128 + quad * 8;

    float4 x0[4], y0[4], x1[4], y1[4];
    s8v an0[4], an1[4];
#pragma unroll
    for (int s = 0; s < 4; s++) {
        x0[s] = *(const float4*)(p0 + s * 32);
        y0[s] = *(const float4*)(p0 + s * 32 + 4);
        x1[s] = *(const float4*)(p1 + s * 32);
        y1[s] = *(const float4*)(p1 + s * 32 + 4);
        an0[s] = *(const s8v*)(q0 + s * 32);
        an1[s] = *(const s8v*)(q1 + s * 32);
    }
    s8v af0[4], af1[4];
#pragma unroll
    for (int s = 0; s < 4; s++) {
        unsigned short u0[8], u1[8];
        u0[0]=f2bf(x0[s].x); u0[1]=f2bf(x0[s].y); u0[2]=f2bf(x0[s].z); u0[3]=f2bf(x0[s].w);
        u0[4]=f2bf(y0[s].x); u0[5]=f2bf(y0[s].y); u0[6]=f2bf(y0[s].z); u0[7]=f2bf(y0[s].w);
        u1[0]=f2bf(x1[s].x); u1[1]=f2bf(x1[s].y); u1[2]=f2bf(x1[s].z); u1[3]=f2bf(x1[s].w);
        u1[4]=f2bf(y1[s].x); u1[5]=f2bf(y1[s].y); u1[6]=f2bf(y1[s].z); u1[7]=f2bf(y1[s].w);
        af0[s] = *(s8v*)u0;
        af1[s] = *(s8v*)u1;
    }

    f32x4 acc0[8], acc1[8];
#pragma unroll
    for (int t = 0; t < 8; t++) {
        acc0[t] = (f32x4){0.f, 0.f, 0.f, 0.f};
        acc1[t] = (f32x4){0.f, 0.f, 0.f, 0.f};
    }

    __syncthreads();

#pragma unroll
    for (int s = 0; s < 4; s++) {
#pragma unroll
        for (int t = 0; t < 8; t++) {
            s8v bf = *(const s8v*)(Bs + ((s * 8 + t) * 64 + lane) * 8);
            acc0[t] = __builtin_amdgcn_mfma_f32_16x16x32_bf16(af0[s], bf, acc0[t], 0, 0, 0);
            acc1[t] = __builtin_amdgcn_mfma_f32_16x16x32_bf16(af1[s], bf, acc1[t], 0, 0, 0);
        }
    }

    __syncthreads();

    {
        const uint4* src = (const uint4*)(Bp + 16384);
#pragma unroll
        for (int i = 0; i < 8; i++)
            Bs4[tid + i * 256] = src[tid + i * 256];
    }
    __syncthreads();

#pragma unroll
    for (int s = 0; s < 4; s++) {
#pragma unroll
        for (int t = 0; t < 8; t++) {
            s8v bf = *(const s8v*)(Bs + ((s * 8 + t) * 64 + lane) * 8);
            acc0[t] = __builtin_amdgcn_mfma_f32_16x16x32_bf16(an0[s], bf, acc0[t], 0, 0, 0);
            acc1[t] = __builtin_amdgcn_mfma_f32_16x16x32_bf16(an1[s], bf, acc1[t], 0, 0, 0);
        }
    }

#pragma unroll
    for (int t = 0; t < 8; t++) {
        float bv = bias[t * 16 + lr];
#pragma unroll
        for (int r = 0; r < 4; r++) {
            int rowa = row0 + quad * 4 + r;
            int rowb = row0 + 16 + quad * 4 + r;
            if (rowa < N_DST) out[(size_t)rowa * D + t * 16 + lr] = acc0[t][r] + bv;
            if (rowb < N_DST) out[(size_t)rowb * D + t * 16 + lr] = acc1[t][r] + bv;
        }
    }
}

extern "C" void kernel_launch(void* const* d_in, const int* in_sizes, int n_in,
                              void* d_out, int out_size, void* d_ws, size_t ws_size,
                              hipStream_t stream) {
    const float* h_src  = (const float*)d_in[0];
    const float* h_dst  = (const float*)d_in[1];
    const int* src_idx  = (const int*)d_in[2];
    const int* dst_idx  = (const int*)d_in[3];
    const float* W      = (const float*)d_in[4];
    const float* b      = (const float*)d_in[5];
    float* out = (float*)d_out;

    // Workspace: Bp | CSR ints | (optional) dense bf16 mirror
    unsigned short* Bp = (unsigned short*)d_ws;         // 32768 u16 = 64 KB
    int* ws_i          = (int*)((char*)d_ws + 65536);
    int* row_start     = ws_i;                          // N_DST+1
    int* cursor        = row_start + (N_DST + 1);       // N_DST
    int* counts        = cursor + N_DST;                // N_DST
    int* block_sums    = counts + N_DST;                // N_SCAN_BLOCKS
    int* edge_src      = block_sums + N_SCAN_BLOCKS;    // N_EDGES

    size_t int_bytes = (size_t)(N_DST + 1 + N_DST + N_DST + N_SCAN_BLOCKS + N_EDGES) * 4;
    size_t mir_off   = (65536 + int_bytes + 255) & ~(size_t)255;
    size_t ws_need   = mir_off + (size_t)N_SRC * D * 2;   // ~29.5 MB
    const bool fused_ok = ws_size >= ws_need;

    hipMemsetAsync(counts, 0, (size_t)N_DST * sizeof(int), stream);

    if (fused_ok) {
        unsigned short* mir = (unsigned short*)((char*)d_ws + mir_off);
        prep<<<HIST_BLOCKS + CVT_BLOCKS + PACKW_BLOCKS, 256, 0, stream>>>(
            dst_idx, counts, h_src, (unsigned int*)mir, 64, W, Bp);
        scan_blocks<<<N_SCAN_BLOCKS, 256, 0, stream>>>(counts, row_start, block_sums);
        add_offsets<<<(N_DST + 255) / 256, 256, 0, stream>>>(row_start, block_sums, cursor);
        scatter_perm<<<(N_EDGES + 255) / 256, 256, 0, stream>>>(src_idx, dst_idx, cursor, edge_src);
        fused_ag<<<(N_DST + 63) / 64, 256, 0, stream>>>(
            h_dst, mir, row_start, edge_src, Bp, b, out);
    } else {
        prep<<<HIST_BLOCKS + CVT_BLOCKS + PACKW_BLOCKS, 256, 0, stream>>>(
            dst_idx, counts, h_src, (unsigned int*)d_out, 128, W, Bp);
        scan_blocks<<<N_SCAN_BLOCKS, 256, 0, stream>>>(counts, row_start, block_sums);
        add_offsets<<<(N_DST + 255) / 256, 256, 0, stream>>>(row_start, block_sums, cursor);
        scatter_perm<<<(N_EDGES + 255) / 256, 256, 0, stream>>>(src_idx, dst_idx, cursor, edge_src);
        aggregate<<<N_DST / 16, 256, 0, stream>>>(
            (const unsigned short*)d_out, row_start, edge_src, (unsigned int*)d_out);
        mfma_gemm<<<(N_DST + 127) / 128, 256, 0, stream>>>(
            h_dst, (const unsigned short*)d_out, Bp, b, out);
    }
}

// Round 6
// 258.190 us; speedup vs baseline: 1.0818x; 1.0098x over previous
//
#include <hip/hip_runtime.h>

#define D 128
#define N_SRC 100000
#define N_DST 100000
#define N_EDGES 640000

#define SCAN_BLK 1024
#define N_SCAN_BLOCKS ((N_DST + SCAN_BLK - 1) / SCAN_BLK)   // 98

#define HIST_BLOCKS ((N_EDGES + 255) / 256)                 // 2500
#define CVT_BLOCKS  ((N_SRC * D / 8) / 256)                 // 6250 (exact)
#define PACKW_BLOCKS 128

typedef __attribute__((ext_vector_type(8))) short s8v;
typedef __attribute__((ext_vector_type(4))) float f32x4;

__device__ __forceinline__ unsigned short f2bf(float f) {
    unsigned int u = __float_as_uint(f);
    u += 0x7fffu + ((u >> 16) & 1u);   // round-to-nearest-even
    return (unsigned short)(u >> 16);
}

__device__ __forceinline__ unsigned int pk2(float a, float b) {
    return (unsigned int)f2bf(a) | ((unsigned int)f2bf(b) << 16);
}

// ---- prep: histogram + h_src->bf16 mirror (dense, ws) + pack W ----------
__global__ __launch_bounds__(256) void prep(
    const int* __restrict__ dst_idx, int* __restrict__ counts,
    const float* __restrict__ h_src, unsigned int* __restrict__ mir32,
    const float* __restrict__ W, unsigned short* __restrict__ Bp)
{
    const int blk = blockIdx.x;
    const int tid = threadIdx.x;
    if (blk < HIST_BLOCKS) {
        int e = blk * 256 + tid;
        if (e < N_EDGES) atomicAdd(&counts[dst_idx[e]], 1);
    } else if (blk < HIST_BLOCKS + CVT_BLOCKS) {
        int id = (blk - HIST_BLOCKS) * 256 + tid;      // [0, 1.6e6)
        size_t e = (size_t)id * 8;
        const float4* p = (const float4*)(h_src + e);
        float4 x = p[0], y = p[1];
        uint4 o;
        o.x = pk2(x.x, x.y); o.y = pk2(x.z, x.w);
        o.z = pk2(y.x, y.y); o.w = pk2(y.z, y.w);
        // dense mirror: row r = id>>4, 64 u32 per row
        *(uint4*)(mir32 + (size_t)(id >> 4) * 64 + (id & 15) * 4) = o;
    } else {
        // pack W into MFMA B-fragment order (bf16)
        int id = (blk - HIST_BLOCKS - CVT_BLOCKS) * 256 + tid;
        if (id < 32768) {
            int j = id & 7;
            int l = (id >> 3) & 63;
            int t = (id >> 9) & 7;
            int s = id >> 12;
            int k = s * 32 + (l >> 4) * 8 + j;
            int n = t * 16 + (l & 15);
            Bp[id] = f2bf(W[k * D + n]);
        }
    }
}

// ---- CSR build ----------------------------------------------------------

__global__ __launch_bounds__(256) void scan_blocks(
    const int* __restrict__ counts, int* __restrict__ row_start,
    int* __restrict__ block_sums)
{
    __shared__ int sh[256];
    const int tid = threadIdx.x;
    const int base = blockIdx.x * SCAN_BLK + tid * 4;
    int v[4];
    int local = 0;
#pragma unroll
    for (int k = 0; k < 4; k++) {
        int idx = base + k;
        v[k] = (idx < N_DST) ? counts[idx] : 0;
        local += v[k];
    }
    sh[tid] = local;
    __syncthreads();
    for (int off = 1; off < 256; off <<= 1) {
        int t = (tid >= off) ? sh[tid - off] : 0;
        __syncthreads();
        sh[tid] += t;
        __syncthreads();
    }
    int run = (tid == 0) ? 0 : sh[tid - 1];
    if (tid == 255) block_sums[blockIdx.x] = sh[255];
#pragma unroll
    for (int k = 0; k < 4; k++) {
        int idx = base + k;
        if (idx < N_DST) row_start[idx] = run;
        run += v[k];
    }
}

__global__ __launch_bounds__(256) void add_offsets(
    int* __restrict__ row_start, const int* __restrict__ block_sums,
    int* __restrict__ cursor)
{
    __shared__ int sh[128];
    const int tid = threadIdx.x;
    if (tid < 128) sh[tid] = (tid < N_SCAN_BLOCKS) ? block_sums[tid] : 0;
    __syncthreads();
    for (int off = 1; off < 128; off <<= 1) {
        int t = (tid < 128 && tid >= off) ? sh[tid - off] : 0;
        __syncthreads();
        if (tid < 128) sh[tid] += t;
        __syncthreads();
    }
    int i = blockIdx.x * 256 + tid;
    if (i < N_DST) {
        int blk = i / SCAN_BLK;
        int off = (blk == 0) ? 0 : sh[blk - 1];
        int v = row_start[i] + off;
        row_start[i] = v;
        cursor[i] = v;
    }
    if (i == 0) row_start[N_DST] = N_EDGES;
}

__global__ __launch_bounds__(256) void scatter_perm(
    const int* __restrict__ src_idx, const int* __restrict__ dst_idx,
    int* __restrict__ cursor, int* __restrict__ edge_src)
{
    int e = blockIdx.x * 256 + threadIdx.x;
    if (e < N_EDGES) {
        int d = dst_idx[e];
        int pos = atomicAdd(&cursor[d], 1);
        edge_src[pos] = src_idx[e];
    }
}

// ================== FUSED gather + projection, TLP-first =================
// Block = 2 waves x 16 rows = 32 rows (3125 blocks = 12.2 per CU).
// Each wave is fully independent: gathers its own 16 rows of h_N from the
// dense bf16 mirror into its own LDS slice (in-wave dep only -> NO
// __syncthreads anywhere), then projects via MFMA with B fragments read
// per-wave from L2 (Bp is 64 KB, L2-hot; R1 measured this equal to LDS
// staging). LDS = 8 KB/block; VGPR capped at 128 -> ~16 waves/CU resident
// vs round-5's ~8.
__global__ __launch_bounds__(128, 4) void fused_ag(
    const float* __restrict__ h_dst,
    const unsigned short* __restrict__ mir,   // dense [N_SRC][128] bf16
    const int* __restrict__ row_start,
    const int* __restrict__ edge_src,
    const unsigned short* __restrict__ Bp,
    const float* __restrict__ bias,
    float* __restrict__ out)
{
    __shared__ uint4 hN4[512];               // 8 KB: h_N[32 rows][256 B]
    char* hN = (char*)hN4;

    const int tid = threadIdx.x;
    const int wave = tid >> 6;               // 0..1
    const int lane = tid & 63;
    const int quad = lane >> 4;
    const int lr = lane & 15;
    const int rw0 = blockIdx.x * 32 + wave * 16;   // wave's first row

    // ---- gather: 4 iterations x 4 rows (one row per 16-lane quad),
    // all rows belong to THIS wave -> LDS write->read is in-wave only.
#pragma unroll
    for (int i = 0; i < 4; i++) {
        int rl = wave * 16 + i * 4 + quad;          // local row 0..31
        int row = blockIdx.x * 32 + rl;
        int start = row_start[row];
        int deg = row_start[row + 1] - start;
        float a[8] = {0.f, 0.f, 0.f, 0.f, 0.f, 0.f, 0.f, 0.f};
        for (int base = 0; base < deg; base += 8) {
            int j = base + (lr & 7);
            int myid = edge_src[start + min(j, deg - 1)];
#pragma unroll
            for (int t = 0; t < 8; t++) {
                int s = __shfl(myid, t, 16);
                uint4 u = *(const uint4*)(mir + (size_t)s * 128 + lr * 8);
                float m = ((base + t) < deg) ? 1.f : 0.f;
                a[0] = fmaf(__uint_as_float(u.x << 16), m, a[0]);
                a[1] = fmaf(__uint_as_float(u.x & 0xffff0000u), m, a[1]);
                a[2] = fmaf(__uint_as_float(u.y << 16), m, a[2]);
                a[3] = fmaf(__uint_as_float(u.y & 0xffff0000u), m, a[3]);
                a[4] = fmaf(__uint_as_float(u.z << 16), m, a[4]);
                a[5] = fmaf(__uint_as_float(u.z & 0xffff0000u), m, a[5]);
                a[6] = fmaf(__uint_as_float(u.w << 16), m, a[6]);
                a[7] = fmaf(__uint_as_float(u.w & 0xffff0000u), m, a[7]);
            }
        }
        float inv = 1.0f / fmaxf((float)deg, 1.0f);
        uint4 o;
        o.x = pk2(a[0] * inv, a[1] * inv);
        o.y = pk2(a[2] * inv, a[3] * inv);
        o.z = pk2(a[4] * inv, a[5] * inv);
        o.w = pk2(a[6] * inv, a[7] * inv);
        // XOR swizzle (bits 4-6) -> max 2-way conflict on the frag reads
        int ba = (rl * 256 + lr * 16) ^ ((rl & 7) << 4);
        *(uint4*)(hN + ba) = o;
    }

    // ---- read back own h_N fragments (in-wave LDS dep; compiler waits)
    s8v an[4];
    {
        int rl = wave * 16 + lr;
#pragma unroll
        for (int s = 0; s < 4; s++) {
            int ba = (rl * 256 + s * 64 + quad * 16) ^ ((rl & 7) << 4);
            an[s] = *(const s8v*)(hN + ba);
        }
    }

    // ---- h_dst loads + convert to bf16 A fragments
    const int r0 = rw0 + lr;                  // N_DST % 32 == 0: in range
    const float* p0 = h_dst + (size_t)r0 * D + quad * 8;
    float4 x0[4], y0[4];
#pragma unroll
    for (int s = 0; s < 4; s++) {
        x0[s] = *(const float4*)(p0 + s * 32);
        y0[s] = *(const float4*)(p0 + s * 32 + 4);
    }
    s8v af0[4];
#pragma unroll
    for (int s = 0; s < 4; s++) {
        unsigned short u0[8];
        u0[0]=f2bf(x0[s].x); u0[1]=f2bf(x0[s].y); u0[2]=f2bf(x0[s].z); u0[3]=f2bf(x0[s].w);
        u0[4]=f2bf(y0[s].x); u0[5]=f2bf(y0[s].y); u0[6]=f2bf(y0[s].z); u0[7]=f2bf(y0[s].w);
        af0[s] = *(s8v*)u0;
    }

    f32x4 acc[8];
#pragma unroll
    for (int t = 0; t < 8; t++) acc[t] = (f32x4){0.f, 0.f, 0.f, 0.f};

    // ---- MFMA: K=0..127 from h_dst frags, K=128..255 from h_N frags;
    // B fragments straight from L2 (identical address stream for all waves)
#pragma unroll
    for (int s = 0; s < 8; s++) {
        s8v a0 = (s < 4) ? af0[s] : an[s - 4];
#pragma unroll
        for (int t = 0; t < 8; t++) {
            s8v bf = *(const s8v*)(Bp + ((size_t)(s * 8 + t) * 64 + lane) * 8);
            acc[t] = __builtin_amdgcn_mfma_f32_16x16x32_bf16(a0, bf, acc[t], 0, 0, 0);
        }
    }

    // ---- epilogue (N_DST divisible by 32: no bounds checks)
#pragma unroll
    for (int t = 0; t < 8; t++) {
        float bv = bias[t * 16 + lr];
#pragma unroll
        for (int r = 0; r < 4; r++) {
            int row = rw0 + quad * 4 + r;
            out[(size_t)row * D + t * 16 + lr] = acc[t][r] + bv;
        }
    }
}

extern "C" void kernel_launch(void* const* d_in, const int* in_sizes, int n_in,
                              void* d_out, int out_size, void* d_ws, size_t ws_size,
                              hipStream_t stream) {
    const float* h_src  = (const float*)d_in[0];
    const float* h_dst  = (const float*)d_in[1];
    const int* src_idx  = (const int*)d_in[2];
    const int* dst_idx  = (const int*)d_in[3];
    const float* W      = (const float*)d_in[4];
    const float* b      = (const float*)d_in[5];
    float* out = (float*)d_out;

    // Workspace: Bp | CSR ints | dense bf16 mirror (~29.5 MB total; round-5
    // run confirmed ws_size covers this: fused path executed)
    unsigned short* Bp = (unsigned short*)d_ws;         // 32768 u16 = 64 KB
    int* ws_i          = (int*)((char*)d_ws + 65536);
    int* row_start     = ws_i;                          // N_DST+1
    int* cursor        = row_start + (N_DST + 1);       // N_DST
    int* counts        = cursor + N_DST;                // N_DST
    int* block_sums    = counts + N_DST;                // N_SCAN_BLOCKS
    int* edge_src      = block_sums + N_SCAN_BLOCKS;    // N_EDGES

    size_t int_bytes = (size_t)(N_DST + 1 + N_DST + N_DST + N_SCAN_BLOCKS + N_EDGES) * 4;
    size_t mir_off   = (65536 + int_bytes + 255) & ~(size_t)255;
    unsigned short* mir = (unsigned short*)((char*)d_ws + mir_off);

    hipMemsetAsync(counts, 0, (size_t)N_DST * sizeof(int), stream);

    prep<<<HIST_BLOCKS + CVT_BLOCKS + PACKW_BLOCKS, 256, 0, stream>>>(
        dst_idx, counts, h_src, (unsigned int*)mir, W, Bp);
    scan_blocks<<<N_SCAN_BLOCKS, 256, 0, stream>>>(counts, row_start, block_sums);
    add_offsets<<<(N_DST + 255) / 256, 256, 0, stream>>>(row_start, block_sums, cursor);
    scatter_perm<<<(N_EDGES + 255) / 256, 256, 0, stream>>>(src_idx, dst_idx, cursor, edge_src);

    fused_ag<<<N_DST / 32, 128, 0, stream>>>(
        h_dst, mir, row_start, edge_src, Bp, b, out);
}